// Round 5
// baseline (30.979 us; speedup 1.0000x reference)
//
#include <hip/hip_runtime.h>
#include <float.h>

#define WINDOW  500
#define NQUADS  125     // 500 floats = 125 float4 per window
#define NSHIFT  125
#define WPB     4       // waves per 256-thread block
#define NWPW    8       // windows per wave (rolling 4-deep pipeline)

// ---- DPP cross-lane primitives (VALU, no LDS) -----------------------------
template <int CTRL, int RM>
__device__ __forceinline__ float dpp_add_step(float x) {
    int t = __builtin_amdgcn_update_dpp(0, __float_as_int(x), CTRL, RM, 0xf, false);
    return x + __int_as_float(t);
}
__device__ __forceinline__ float scan64_add(float x) {
    x = dpp_add_step<0x111, 0xf>(x);   // row_shr:1
    x = dpp_add_step<0x112, 0xf>(x);   // row_shr:2
    x = dpp_add_step<0x114, 0xf>(x);   // row_shr:4
    x = dpp_add_step<0x118, 0xf>(x);   // row_shr:8
    x = dpp_add_step<0x142, 0xa>(x);   // row_bcast:15 -> rows 1,3
    x = dpp_add_step<0x143, 0xc>(x);   // row_bcast:31 -> rows 2,3
    return x;                          // lane63 = wave total
}
template <int CTRL, int RM>
__device__ __forceinline__ float dpp_min_step(float x) {
    int t = __builtin_amdgcn_update_dpp(0x7f800000, __float_as_int(x), CTRL, RM, 0xf, false);
    return fminf(x, __int_as_float(t));
}
__device__ __forceinline__ float wave_min64(float x) {
    x = dpp_min_step<0x111, 0xf>(x);
    x = dpp_min_step<0x112, 0xf>(x);
    x = dpp_min_step<0x114, 0xf>(x);
    x = dpp_min_step<0x118, 0xf>(x);
    x = dpp_min_step<0x142, 0xa>(x);
    x = dpp_min_step<0x143, 0xc>(x);
    return __int_as_float(__builtin_amdgcn_readlane(__float_as_int(x), 63));
}
__device__ __forceinline__ float rl63(float x) {
    return __int_as_float(__builtin_amdgcn_readlane(__float_as_int(x), 63));
}
__device__ __forceinline__ float frcp(float x) {
    float r = __builtin_amdgcn_rcpf(x);
    return r * (2.0f - x * r);   // 1 Newton step, ~1e-7 rel err
}

__device__ __forceinline__ float ccc_eval(float Sp, float Spp, float Spg,
                                          float m_g, float var_g) {
    const float invW   = 1.0f / (float)WINDOW;
    const float invWm1 = 1.0f / (float)(WINDOW - 1);
    float m_p   = Sp * invW;
    float var_p = (Spp - (float)WINDOW * m_p * m_p) * invWm1;
    float cov   = Spg * invW - m_p * m_g;
    float d     = m_g - m_p;
    return 2.0f * cov * frcp(var_g + var_p + d * d);
}

struct Win { float4 pa, ga, pb, gb; };

__device__ __forceinline__ void load_win(const float4* __restrict__ pred4,
                                         const float4* __restrict__ gt4,
                                         int w, int lane, Win& d)
{
    const float4* p4 = pred4 + (size_t)w * NQUADS;
    const float4* g4 = gt4   + (size_t)w * NQUADS;
    d.pa = p4[lane];
    d.ga = g4[lane];
    d.pb = make_float4(0.f, 0.f, 0.f, 0.f);
    d.gb = make_float4(0.f, 0.f, 0.f, 0.f);
    if (lane < NQUADS - 64) { d.pb = p4[64 + lane]; d.gb = g4[64 + lane]; }
}

// Full per-window pipeline; returns wave-uniform min-ccc over the 125 shifts.
__device__ __forceinline__ float compute_win(const Win& d, int lane)
{
    const float4 pa = d.pa, ga = d.ga, pb = d.pb, gb = d.gb;

    const float qp  = pa.x + pa.y + pa.z + pa.w;
    const float qpp = pa.x*pa.x + pa.y*pa.y + pa.z*pa.z + pa.w*pa.w;
    const float qpg = pa.x*ga.x + pa.y*ga.y + pa.z*ga.z + pa.w*ga.w;
    const float r1p  = pb.x + pb.y + pb.z + pb.w;
    const float r1pp = pb.x*pb.x + pb.y*pb.y + pb.z*pb.z + pb.w*pb.w;
    const float r1pg = pb.x*gb.x + pb.y*gb.y + pb.z*gb.z + pb.w*gb.w;
    const float lg  = ga.x + ga.y + ga.z + ga.w + gb.x + gb.y + gb.z + gb.w;
    const float lgg = ga.x*ga.x + ga.y*ga.y + ga.z*ga.z + ga.w*ga.w
                    + gb.x*gb.x + gb.y*gb.y + gb.z*gb.z + gb.w*gb.w;

    float c_p  = scan64_add(qp);
    float c_pp = scan64_add(qpp);
    float c_pg = scan64_add(qpg);
    const float sp  = rl63(c_p)  + rl63(scan64_add(r1p));
    const float spp = rl63(c_pp) + rl63(scan64_add(r1pp));
    const float spg = rl63(c_pg) + rl63(scan64_add(r1pg));
    const float sg  = rl63(scan64_add(lg));
    const float sgg = rl63(scan64_add(lgg));

    const float invW   = 1.0f / (float)WINDOW;
    const float invWm1 = 1.0f / (float)(WINDOW - 1);
    const float m_g   = sg * invW;
    const float var_g = (sgg - (float)WINDOW * m_g * m_g) * invWm1;

    float cmin = FLT_MAX;
    if (lane < 32) {
        float Sp  = sp  - (c_p  - qp);
        float Spp = spp - (c_pp - qpp);
        float Spg = spg - (c_pg - qpg);
        const int base = lane * 4;
        cmin = ccc_eval(Sp, Spp, Spg, m_g, var_g);                    // r=0
        Sp -= pa.x; Spp -= pa.x*pa.x; Spg -= pa.x*ga.x;               // r=1
        if (base + 1 < NSHIFT) cmin = fminf(cmin, ccc_eval(Sp, Spp, Spg, m_g, var_g));
        Sp -= pa.y; Spp -= pa.y*pa.y; Spg -= pa.y*ga.y;               // r=2
        if (base + 2 < NSHIFT) cmin = fminf(cmin, ccc_eval(Sp, Spp, Spg, m_g, var_g));
        Sp -= pa.z; Spp -= pa.z*pa.z; Spg -= pa.z*ga.z;               // r=3
        if (base + 3 < NSHIFT) cmin = fminf(cmin, ccc_eval(Sp, Spp, Spg, m_g, var_g));
    }
    return wave_min64(cmin);
}

template <bool TWO_STAGE>
__global__ __launch_bounds__(256, 4) void window_ccc_kernel(
    const float4* __restrict__ pred4,
    const float4* __restrict__ gt4,
    float* __restrict__ block_out,
    int num_wins)
{
    __shared__ float s_sum[WPB];
    const int wave   = threadIdx.x >> 6;
    const int lane   = threadIdx.x & 63;
    const int gwaves = gridDim.x * WPB;
    const int gwave  = blockIdx.x * WPB + wave;

    int  w0 = gwave,              w1 = gwave + gwaves,
         w2 = gwave + 2 * gwaves, w3 = gwave + 3 * gwaves,
         w4 = gwave + 4 * gwaves, w5 = gwave + 5 * gwaves,
         w6 = gwave + 6 * gwaves, w7 = gwave + 7 * gwaves;
    const bool v0 = w0 < num_wins, v1 = w1 < num_wins, v2 = w2 < num_wins,
               v3 = w3 < num_wins, v4 = w4 < num_wins, v5 = w5 < num_wins,
               v6 = w6 < num_wins, v7 = w7 < num_wins;

    Win A, B, C, D;
    load_win(pred4, gt4, v0 ? w0 : 0, lane, A);
    load_win(pred4, gt4, v1 ? w1 : 0, lane, B);
    load_win(pred4, gt4, v2 ? w2 : 0, lane, C);
    load_win(pred4, gt4, v3 ? w3 : 0, lane, D);
    __builtin_amdgcn_sched_barrier(0);   // pin: all 16 loads issued before any compute

    float ws = 0.f;
    { float cm = compute_win(A, lane); if (v0) ws += cm; }
    load_win(pred4, gt4, v4 ? w4 : 0, lane, A);
    __builtin_amdgcn_sched_barrier(0);   // A(w4) loads issue before compute(B) body ends
    { float cm = compute_win(B, lane); if (v1) ws += cm; }
    load_win(pred4, gt4, v5 ? w5 : 0, lane, B);
    __builtin_amdgcn_sched_barrier(0);
    { float cm = compute_win(C, lane); if (v2) ws += cm; }
    load_win(pred4, gt4, v6 ? w6 : 0, lane, C);
    __builtin_amdgcn_sched_barrier(0);
    { float cm = compute_win(D, lane); if (v3) ws += cm; }
    load_win(pred4, gt4, v7 ? w7 : 0, lane, D);
    __builtin_amdgcn_sched_barrier(0);
    { float cm = compute_win(A, lane); if (v4) ws += cm; }
    { float cm = compute_win(B, lane); if (v5) ws += cm; }
    { float cm = compute_win(C, lane); if (v6) ws += cm; }
    { float cm = compute_win(D, lane); if (v7) ws += cm; }

    if (lane == 0) s_sum[wave] = ws;
    __syncthreads();
    if (threadIdx.x == 0) {
        float s = s_sum[0] + s_sum[1] + s_sum[2] + s_sum[3];
        if (TWO_STAGE) block_out[blockIdx.x] = s;
        else           atomicAdd(block_out, s);
    }
}

__global__ __launch_bounds__(256) void window_ccc_finalize(
    const float* __restrict__ block_sums, int nblocks,
    float* __restrict__ out, int num_wins)
{
    float s = 0.f;
    for (int i = threadIdx.x; i < nblocks; i += 256) s += block_sums[i];
    #pragma unroll
    for (int off = 32; off >= 1; off >>= 1) s += __shfl_xor(s, off);
    __shared__ float ws[4];
    const int wave = threadIdx.x >> 6, lane = threadIdx.x & 63;
    if (lane == 0) ws[wave] = s;
    __syncthreads();
    if (threadIdx.x == 0)
        out[0] = 1.0f - (ws[0] + ws[1] + ws[2] + ws[3]) / (float)num_wins;
}

extern "C" void kernel_launch(void* const* d_in, const int* in_sizes, int n_in,
                              void* d_out, int out_size, void* d_ws, size_t ws_size,
                              hipStream_t stream) {
    const float4* pred4 = (const float4*)d_in[0];
    const float4* gt4   = (const float4*)d_in[1];
    float* out = (float*)d_out;
    float* ws  = (float*)d_ws;

    const int L = in_sizes[0];
    const int num_wins = L / WINDOW;
    const int wins_per_block = WPB * NWPW;                    // 32
    const int nblocks = (num_wins + wins_per_block - 1) / wins_per_block;

    if (ws_size >= (size_t)nblocks * sizeof(float)) {
        window_ccc_kernel<true><<<nblocks, 256, 0, stream>>>(pred4, gt4, ws, num_wins);
        window_ccc_finalize<<<1, 256, 0, stream>>>(ws, nblocks, out, num_wins);
    } else {
        hipMemsetAsync(ws, 0, sizeof(float), stream);
        window_ccc_kernel<false><<<nblocks, 256, 0, stream>>>(pred4, gt4, ws, num_wins);
        window_ccc_finalize<<<1, 256, 0, stream>>>(ws, 1, out, num_wins);
    }
}

// Round 6
// 30.526 us; speedup vs baseline: 1.0148x; 1.0148x over previous
//
#include <hip/hip_runtime.h>
#include <float.h>

#define WINDOW  500
#define NQUADS  125     // 500 floats = 125 float4 per window
#define NSHIFT  125
#define WPB     4       // waves per 256-thread block
#define NWPW    8       // windows per wave (4-deep asm-pinned pipeline)

// ---- DPP cross-lane primitives (VALU, no LDS) -----------------------------
template <int CTRL, int RM>
__device__ __forceinline__ float dpp_add_step(float x) {
    int t = __builtin_amdgcn_update_dpp(0, __float_as_int(x), CTRL, RM, 0xf, false);
    return x + __int_as_float(t);
}
__device__ __forceinline__ float scan64_add(float x) {
    x = dpp_add_step<0x111, 0xf>(x);   // row_shr:1
    x = dpp_add_step<0x112, 0xf>(x);   // row_shr:2
    x = dpp_add_step<0x114, 0xf>(x);   // row_shr:4
    x = dpp_add_step<0x118, 0xf>(x);   // row_shr:8
    x = dpp_add_step<0x142, 0xa>(x);   // row_bcast:15 -> rows 1,3
    x = dpp_add_step<0x143, 0xc>(x);   // row_bcast:31 -> rows 2,3
    return x;                          // lane63 = wave total
}
template <int CTRL, int RM>
__device__ __forceinline__ float dpp_min_step(float x) {
    int t = __builtin_amdgcn_update_dpp(0x7f800000, __float_as_int(x), CTRL, RM, 0xf, false);
    return fminf(x, __int_as_float(t));
}
__device__ __forceinline__ float wave_min64(float x) {
    x = dpp_min_step<0x111, 0xf>(x);
    x = dpp_min_step<0x112, 0xf>(x);
    x = dpp_min_step<0x114, 0xf>(x);
    x = dpp_min_step<0x118, 0xf>(x);
    x = dpp_min_step<0x142, 0xa>(x);
    x = dpp_min_step<0x143, 0xc>(x);
    return __int_as_float(__builtin_amdgcn_readlane(__float_as_int(x), 63));
}
__device__ __forceinline__ float rl63(float x) {
    return __int_as_float(__builtin_amdgcn_readlane(__float_as_int(x), 63));
}
__device__ __forceinline__ float frcp(float x) {
    float r = __builtin_amdgcn_rcpf(x);
    return r * (2.0f - x * r);   // 1 Newton step, ~1e-7 rel err
}

__device__ __forceinline__ float ccc_eval(float Sp, float Spp, float Spg,
                                          float m_g, float var_g) {
    const float invW   = 1.0f / (float)WINDOW;
    const float invWm1 = 1.0f / (float)(WINDOW - 1);
    float m_p   = Sp * invW;
    float var_p = (Spp - (float)WINDOW * m_p * m_p) * invWm1;
    float cov   = Spg * invW - m_p * m_g;
    float d     = m_g - m_p;
    return 2.0f * cov * frcp(var_g + var_p + d * d);
}

// Inline-asm 16B load: an asm volatile cannot be sunk/dissolved by the
// compiler, so the software pipeline's issue points are pinned.
__device__ __forceinline__ float4 gload16(const float4* p) {
    float4 r;
    asm volatile("global_load_dwordx4 %0, %1, off" : "=v"(r) : "v"(p) : "memory");
    return r;
}
#define WAIT_VMCNT(n) asm volatile("s_waitcnt vmcnt(" #n ")" ::: "memory"); \
                      __builtin_amdgcn_sched_barrier(0)

struct Win { float4 pa, ga, pb, gb; };

// Branch-free: 4 loads per window, tail lanes (61..63) clamp their address to
// the window start (always valid) and their values are zeroed at use.
__device__ __forceinline__ void load_win(const float4* __restrict__ pred4,
                                         const float4* __restrict__ gt4,
                                         int w, int lane, Win& d)
{
    const float4* p4 = pred4 + (size_t)w * NQUADS;
    const float4* g4 = gt4   + (size_t)w * NQUADS;
    const int off1 = (lane < NQUADS - 64) ? 64 + lane : 0;
    d.pa = gload16(p4 + lane);
    d.ga = gload16(g4 + lane);
    d.pb = gload16(p4 + off1);
    d.gb = gload16(g4 + off1);
}

// Full per-window pipeline; returns wave-uniform min-ccc over the 125 shifts.
__device__ __forceinline__ float compute_win(const Win& d, int lane)
{
    const bool tail = (lane < NQUADS - 64);
    const float4 pa = d.pa, ga = d.ga;
    const float4 pb = tail ? d.pb : make_float4(0.f, 0.f, 0.f, 0.f);
    const float4 gb = tail ? d.gb : make_float4(0.f, 0.f, 0.f, 0.f);

    const float qp  = pa.x + pa.y + pa.z + pa.w;
    const float qpp = pa.x*pa.x + pa.y*pa.y + pa.z*pa.z + pa.w*pa.w;
    const float qpg = pa.x*ga.x + pa.y*ga.y + pa.z*ga.z + pa.w*ga.w;
    const float r1p  = pb.x + pb.y + pb.z + pb.w;
    const float r1pp = pb.x*pb.x + pb.y*pb.y + pb.z*pb.z + pb.w*pb.w;
    const float r1pg = pb.x*gb.x + pb.y*gb.y + pb.z*gb.z + pb.w*gb.w;
    const float lg  = ga.x + ga.y + ga.z + ga.w + gb.x + gb.y + gb.z + gb.w;
    const float lgg = ga.x*ga.x + ga.y*ga.y + ga.z*ga.z + ga.w*ga.w
                    + gb.x*gb.x + gb.y*gb.y + gb.z*gb.z + gb.w*gb.w;

    float c_p  = scan64_add(qp);
    float c_pp = scan64_add(qpp);
    float c_pg = scan64_add(qpg);
    const float sp  = rl63(c_p)  + rl63(scan64_add(r1p));
    const float spp = rl63(c_pp) + rl63(scan64_add(r1pp));
    const float spg = rl63(c_pg) + rl63(scan64_add(r1pg));
    const float sg  = rl63(scan64_add(lg));
    const float sgg = rl63(scan64_add(lgg));

    const float invW   = 1.0f / (float)WINDOW;
    const float invWm1 = 1.0f / (float)(WINDOW - 1);
    const float m_g   = sg * invW;
    const float var_g = (sgg - (float)WINDOW * m_g * m_g) * invWm1;

    float cmin = FLT_MAX;
    if (lane < 32) {
        float Sp  = sp  - (c_p  - qp);
        float Spp = spp - (c_pp - qpp);
        float Spg = spg - (c_pg - qpg);
        const int base = lane * 4;
        cmin = ccc_eval(Sp, Spp, Spg, m_g, var_g);                    // r=0
        Sp -= pa.x; Spp -= pa.x*pa.x; Spg -= pa.x*ga.x;               // r=1
        if (base + 1 < NSHIFT) cmin = fminf(cmin, ccc_eval(Sp, Spp, Spg, m_g, var_g));
        Sp -= pa.y; Spp -= pa.y*pa.y; Spg -= pa.y*ga.y;               // r=2
        if (base + 2 < NSHIFT) cmin = fminf(cmin, ccc_eval(Sp, Spp, Spg, m_g, var_g));
        Sp -= pa.z; Spp -= pa.z*pa.z; Spg -= pa.z*ga.z;               // r=3
        if (base + 3 < NSHIFT) cmin = fminf(cmin, ccc_eval(Sp, Spp, Spg, m_g, var_g));
    }
    return wave_min64(cmin);
}

template <bool TWO_STAGE>
__global__ __launch_bounds__(256, 4) void window_ccc_kernel(
    const float4* __restrict__ pred4,
    const float4* __restrict__ gt4,
    float* __restrict__ block_out,
    int num_wins)
{
    __shared__ float s_sum[WPB];
    const int wave   = threadIdx.x >> 6;
    const int lane   = threadIdx.x & 63;
    const int gwaves = gridDim.x * WPB;
    const int gwave  = blockIdx.x * WPB + wave;

    int  w0 = gwave,              w1 = gwave + gwaves,
         w2 = gwave + 2 * gwaves, w3 = gwave + 3 * gwaves,
         w4 = gwave + 4 * gwaves, w5 = gwave + 5 * gwaves,
         w6 = gwave + 6 * gwaves, w7 = gwave + 7 * gwaves;
    const bool v0 = w0 < num_wins, v1 = w1 < num_wins, v2 = w2 < num_wins,
               v3 = w3 < num_wins, v4 = w4 < num_wins, v5 = w5 < num_wins,
               v6 = w6 < num_wins, v7 = w7 < num_wins;

    Win A, B, C, D;
    load_win(pred4, gt4, v0 ? w0 : 0, lane, A);   //  4 out
    load_win(pred4, gt4, v1 ? w1 : 0, lane, B);   //  8 out
    load_win(pred4, gt4, v2 ? w2 : 0, lane, C);   // 12 out
    load_win(pred4, gt4, v3 ? w3 : 0, lane, D);   // 16 out

    float ws = 0.f;
    WAIT_VMCNT(12);                               // A ready
    { float cm = compute_win(A, lane); if (v0) ws += cm; }
    load_win(pred4, gt4, v4 ? w4 : 0, lane, A);   // 16 out
    WAIT_VMCNT(12);                               // B ready
    { float cm = compute_win(B, lane); if (v1) ws += cm; }
    load_win(pred4, gt4, v5 ? w5 : 0, lane, B);
    WAIT_VMCNT(12);                               // C ready
    { float cm = compute_win(C, lane); if (v2) ws += cm; }
    load_win(pred4, gt4, v6 ? w6 : 0, lane, C);
    WAIT_VMCNT(12);                               // D ready
    { float cm = compute_win(D, lane); if (v3) ws += cm; }
    load_win(pred4, gt4, v7 ? w7 : 0, lane, D);
    WAIT_VMCNT(12);                               // A(w4) ready
    { float cm = compute_win(A, lane); if (v4) ws += cm; }
    WAIT_VMCNT(8);                                // B(w5) ready
    { float cm = compute_win(B, lane); if (v5) ws += cm; }
    WAIT_VMCNT(4);                                // C(w6) ready
    { float cm = compute_win(C, lane); if (v6) ws += cm; }
    WAIT_VMCNT(0);                                // D(w7) ready
    { float cm = compute_win(D, lane); if (v7) ws += cm; }

    if (lane == 0) s_sum[wave] = ws;
    __syncthreads();
    if (threadIdx.x == 0) {
        float s = s_sum[0] + s_sum[1] + s_sum[2] + s_sum[3];
        if (TWO_STAGE) block_out[blockIdx.x] = s;
        else           atomicAdd(block_out, s);
    }
}

__global__ __launch_bounds__(256) void window_ccc_finalize(
    const float* __restrict__ block_sums, int nblocks,
    float* __restrict__ out, int num_wins)
{
    float s = 0.f;
    for (int i = threadIdx.x; i < nblocks; i += 256) s += block_sums[i];
    #pragma unroll
    for (int off = 32; off >= 1; off >>= 1) s += __shfl_xor(s, off);
    __shared__ float ws[4];
    const int wave = threadIdx.x >> 6, lane = threadIdx.x & 63;
    if (lane == 0) ws[wave] = s;
    __syncthreads();
    if (threadIdx.x == 0)
        out[0] = 1.0f - (ws[0] + ws[1] + ws[2] + ws[3]) / (float)num_wins;
}

extern "C" void kernel_launch(void* const* d_in, const int* in_sizes, int n_in,
                              void* d_out, int out_size, void* d_ws, size_t ws_size,
                              hipStream_t stream) {
    const float4* pred4 = (const float4*)d_in[0];
    const float4* gt4   = (const float4*)d_in[1];
    float* out = (float*)d_out;
    float* ws  = (float*)d_ws;

    const int L = in_sizes[0];
    const int num_wins = L / WINDOW;
    const int wins_per_block = WPB * NWPW;                    // 32
    const int nblocks = (num_wins + wins_per_block - 1) / wins_per_block;

    if (ws_size >= (size_t)nblocks * sizeof(float)) {
        window_ccc_kernel<true><<<nblocks, 256, 0, stream>>>(pred4, gt4, ws, num_wins);
        window_ccc_finalize<<<1, 256, 0, stream>>>(ws, nblocks, out, num_wins);
    } else {
        hipMemsetAsync(ws, 0, sizeof(float), stream);
        window_ccc_kernel<false><<<nblocks, 256, 0, stream>>>(pred4, gt4, ws, num_wins);
        window_ccc_finalize<<<1, 256, 0, stream>>>(ws, 1, out, num_wins);
    }
}

// Round 7
// 29.457 us; speedup vs baseline: 1.0516x; 1.0363x over previous
//
#include <hip/hip_runtime.h>
#include <float.h>

#define WINDOW  500
#define NQUADS  125     // 500 floats = 125 float4 per window
#define NSHIFT  125
#define WPB     4       // waves per 256-thread block
#define NWPW    4       // windows per wave, 2-deep A/B pipeline

// ---- DPP cross-lane primitives (VALU, no LDS) -----------------------------
template <int CTRL, int RM>
__device__ __forceinline__ float dpp_add_step(float x) {
    int t = __builtin_amdgcn_update_dpp(0, __float_as_int(x), CTRL, RM, 0xf, false);
    return x + __int_as_float(t);
}
__device__ __forceinline__ float scan64_add(float x) {
    x = dpp_add_step<0x111, 0xf>(x);   // row_shr:1
    x = dpp_add_step<0x112, 0xf>(x);   // row_shr:2
    x = dpp_add_step<0x114, 0xf>(x);   // row_shr:4
    x = dpp_add_step<0x118, 0xf>(x);   // row_shr:8
    x = dpp_add_step<0x142, 0xa>(x);   // row_bcast:15 -> rows 1,3
    x = dpp_add_step<0x143, 0xc>(x);   // row_bcast:31 -> rows 2,3
    return x;                          // lane63 = wave total
}
template <int CTRL, int RM>
__device__ __forceinline__ float dpp_min_step(float x) {
    int t = __builtin_amdgcn_update_dpp(0x7f800000, __float_as_int(x), CTRL, RM, 0xf, false);
    return fminf(x, __int_as_float(t));
}
__device__ __forceinline__ float wave_min64(float x) {
    x = dpp_min_step<0x111, 0xf>(x);
    x = dpp_min_step<0x112, 0xf>(x);
    x = dpp_min_step<0x114, 0xf>(x);
    x = dpp_min_step<0x118, 0xf>(x);
    x = dpp_min_step<0x142, 0xa>(x);
    x = dpp_min_step<0x143, 0xc>(x);
    return __int_as_float(__builtin_amdgcn_readlane(__float_as_int(x), 63));
}
__device__ __forceinline__ float rl63(float x) {
    return __int_as_float(__builtin_amdgcn_readlane(__float_as_int(x), 63));
}
__device__ __forceinline__ float frcp(float x) {
    float r = __builtin_amdgcn_rcpf(x);
    return r * (2.0f - x * r);   // 1 Newton step, ~1e-7 rel err
}

__device__ __forceinline__ float ccc_eval(float Sp, float Spp, float Spg,
                                          float m_g, float var_g) {
    const float invW   = 1.0f / (float)WINDOW;
    const float invWm1 = 1.0f / (float)(WINDOW - 1);
    float m_p   = Sp * invW;
    float var_p = (Spp - (float)WINDOW * m_p * m_p) * invWm1;
    float cov   = Spg * invW - m_p * m_g;
    float d     = m_g - m_p;
    return 2.0f * cov * frcp(var_g + var_p + d * d);
}

// Inline-asm 16B load: cannot be sunk or reordered by the compiler.
__device__ __forceinline__ float4 gload16(const float4* p) {
    float4 r;
    asm volatile("global_load_dwordx4 %0, %1, off" : "=v"(r) : "v"(p) : "memory");
    return r;
}
// Rule #18: sched_barrier after waitcnt so register-only consumers can't hoist.
#define WAIT_VMCNT(n) asm volatile("s_waitcnt vmcnt(" #n ")" ::: "memory"); \
                      __builtin_amdgcn_sched_barrier(0)

struct Win { float4 pa, ga, pb, gb; };

// Branch-free: tail lanes (61..63) clamp to quad 0; values zeroed at use.
__device__ __forceinline__ void load_win(const float4* __restrict__ pred4,
                                         const float4* __restrict__ gt4,
                                         int w, int lane, Win& d)
{
    const float4* p4 = pred4 + (size_t)w * NQUADS;
    const float4* g4 = gt4   + (size_t)w * NQUADS;
    const int off1 = (lane < NQUADS - 64) ? 64 + lane : 0;
    d.pa = gload16(p4 + lane);
    d.ga = gload16(g4 + lane);
    d.pb = gload16(p4 + off1);
    d.gb = gload16(g4 + off1);
}

__device__ __forceinline__ float compute_win(const Win& d, int lane)
{
    const bool tail = (lane < NQUADS - 64);
    const float4 pa = d.pa, ga = d.ga;
    const float4 pb = tail ? d.pb : make_float4(0.f, 0.f, 0.f, 0.f);
    const float4 gb = tail ? d.gb : make_float4(0.f, 0.f, 0.f, 0.f);

    const float qp  = pa.x + pa.y + pa.z + pa.w;
    const float qpp = pa.x*pa.x + pa.y*pa.y + pa.z*pa.z + pa.w*pa.w;
    const float qpg = pa.x*ga.x + pa.y*ga.y + pa.z*ga.z + pa.w*ga.w;
    const float r1p  = pb.x + pb.y + pb.z + pb.w;
    const float r1pp = pb.x*pb.x + pb.y*pb.y + pb.z*pb.z + pb.w*pb.w;
    const float r1pg = pb.x*gb.x + pb.y*gb.y + pb.z*gb.z + pb.w*gb.w;
    const float lg  = ga.x + ga.y + ga.z + ga.w + gb.x + gb.y + gb.z + gb.w;
    const float lgg = ga.x*ga.x + ga.y*ga.y + ga.z*ga.z + ga.w*ga.w
                    + gb.x*gb.x + gb.y*gb.y + gb.z*gb.z + gb.w*gb.w;

    float c_p  = scan64_add(qp);
    float c_pp = scan64_add(qpp);
    float c_pg = scan64_add(qpg);
    const float sp  = rl63(c_p)  + rl63(scan64_add(r1p));
    const float spp = rl63(c_pp) + rl63(scan64_add(r1pp));
    const float spg = rl63(c_pg) + rl63(scan64_add(r1pg));
    const float sg  = rl63(scan64_add(lg));
    const float sgg = rl63(scan64_add(lgg));

    const float invW   = 1.0f / (float)WINDOW;
    const float invWm1 = 1.0f / (float)(WINDOW - 1);
    const float m_g   = sg * invW;
    const float var_g = (sgg - (float)WINDOW * m_g * m_g) * invWm1;

    float cmin = FLT_MAX;
    if (lane < 32) {
        float Sp  = sp  - (c_p  - qp);
        float Spp = spp - (c_pp - qpp);
        float Spg = spg - (c_pg - qpg);
        const int base = lane * 4;
        cmin = ccc_eval(Sp, Spp, Spg, m_g, var_g);                    // r=0
        Sp -= pa.x; Spp -= pa.x*pa.x; Spg -= pa.x*ga.x;               // r=1
        if (base + 1 < NSHIFT) cmin = fminf(cmin, ccc_eval(Sp, Spp, Spg, m_g, var_g));
        Sp -= pa.y; Spp -= pa.y*pa.y; Spg -= pa.y*ga.y;               // r=2
        if (base + 2 < NSHIFT) cmin = fminf(cmin, ccc_eval(Sp, Spp, Spg, m_g, var_g));
        Sp -= pa.z; Spp -= pa.z*pa.z; Spg -= pa.z*ga.z;               // r=3
        if (base + 3 < NSHIFT) cmin = fminf(cmin, ccc_eval(Sp, Spp, Spg, m_g, var_g));
    }
    return wave_min64(cmin);
}

template <bool TWO_STAGE>
__global__ __launch_bounds__(256, 6) void window_ccc_kernel(
    const float4* __restrict__ pred4,
    const float4* __restrict__ gt4,
    float* __restrict__ block_out,
    int num_wins)
{
    __shared__ float s_sum[WPB];
    const int wave   = threadIdx.x >> 6;
    const int lane   = threadIdx.x & 63;
    const int gwaves = gridDim.x * WPB;
    const int gwave  = blockIdx.x * WPB + wave;

    const int  wmax = num_wins - 1;
    int  w0 = gwave,              w1 = gwave + gwaves,
         w2 = gwave + 2 * gwaves, w3 = gwave + 3 * gwaves;
    const bool v0 = w0 <= wmax, v1 = w1 <= wmax, v2 = w2 <= wmax, v3 = w3 <= wmax;
    w0 = v0 ? w0 : wmax; w1 = v1 ? w1 : wmax;
    w2 = v2 ? w2 : wmax; w3 = v3 ? w3 : wmax;

    Win A, B;
    load_win(pred4, gt4, w0, lane, A);            //  4 out
    load_win(pred4, gt4, w1, lane, B);            //  8 out

    float ws = 0.f;
    WAIT_VMCNT(4);                                // A(w0) ready
    { float cm = compute_win(A, lane); if (v0) ws += cm; }
    load_win(pred4, gt4, w2, lane, A);            //  8 out
    WAIT_VMCNT(4);                                // B(w1) ready
    { float cm = compute_win(B, lane); if (v1) ws += cm; }
    load_win(pred4, gt4, w3, lane, B);            //  8 out
    WAIT_VMCNT(4);                                // A(w2) ready
    { float cm = compute_win(A, lane); if (v2) ws += cm; }
    WAIT_VMCNT(0);                                // B(w3) ready
    { float cm = compute_win(B, lane); if (v3) ws += cm; }

    if (lane == 0) s_sum[wave] = ws;
    __syncthreads();
    if (threadIdx.x == 0) {
        float s = s_sum[0] + s_sum[1] + s_sum[2] + s_sum[3];
        if (TWO_STAGE) block_out[blockIdx.x] = s;
        else           atomicAdd(block_out, s);
    }
}

__global__ __launch_bounds__(256) void window_ccc_finalize(
    const float* __restrict__ block_sums, int nblocks,
    float* __restrict__ out, int num_wins)
{
    float s = 0.f;
    for (int i = threadIdx.x; i < nblocks; i += 256) s += block_sums[i];
    #pragma unroll
    for (int off = 32; off >= 1; off >>= 1) s += __shfl_xor(s, off);
    __shared__ float ws[4];
    const int wave = threadIdx.x >> 6, lane = threadIdx.x & 63;
    if (lane == 0) ws[wave] = s;
    __syncthreads();
    if (threadIdx.x == 0)
        out[0] = 1.0f - (ws[0] + ws[1] + ws[2] + ws[3]) / (float)num_wins;
}

extern "C" void kernel_launch(void* const* d_in, const int* in_sizes, int n_in,
                              void* d_out, int out_size, void* d_ws, size_t ws_size,
                              hipStream_t stream) {
    const float4* pred4 = (const float4*)d_in[0];
    const float4* gt4   = (const float4*)d_in[1];
    float* out = (float*)d_out;
    float* ws  = (float*)d_ws;

    const int L = in_sizes[0];
    const int num_wins = L / WINDOW;
    const int wins_per_block = WPB * NWPW;                    // 16
    const int nblocks = (num_wins + wins_per_block - 1) / wins_per_block;  // 2048

    if (ws_size >= (size_t)nblocks * sizeof(float)) {
        window_ccc_kernel<true><<<nblocks, 256, 0, stream>>>(pred4, gt4, ws, num_wins);
        window_ccc_finalize<<<1, 256, 0, stream>>>(ws, nblocks, out, num_wins);
    } else {
        hipMemsetAsync(ws, 0, sizeof(float), stream);
        window_ccc_kernel<false><<<nblocks, 256, 0, stream>>>(pred4, gt4, ws, num_wins);
        window_ccc_finalize<<<1, 256, 0, stream>>>(ws, 1, out, num_wins);
    }
}